// Round 2
// baseline (757.904 us; speedup 1.0000x reference)
//
#include <hip/hip_runtime.h>
#include <hip/hip_bf16.h>

#define DIM 128

typedef __attribute__((ext_vector_type(8))) __bf16 bf16x8;
typedef __attribute__((ext_vector_type(4))) float f32x4;

// ---------------------------------------------------------------------------
// Probe: decide whether index buffer is int32 or int64.
// If int64 (values in [0,1e5)), every odd 32-bit word is 0. For random int32
// indices the OR of 800K odd words is ~never 0. flag=1 => int32 layout.
// ---------------------------------------------------------------------------
__global__ void idx_probe_kernel(const unsigned* __restrict__ idx32,
                                 unsigned* __restrict__ flag, int n) {
  unsigned v = 0;
  const int stride = gridDim.x * blockDim.x;
  for (int i = blockIdx.x * blockDim.x + threadIdx.x; i < n; i += stride)
    v |= idx32[2 * i + 1];
  if (v) atomicOr(flag, 1u);
}

// ---------------------------------------------------------------------------
// Fused: h = relu(e @ W^T + b); atomic segment-sum into out[index[n]].
//
// Pipelining: per iteration the vmem queue is
//   [eload(i) idx(i)] [eload(i+1) idx(i+1)] [atomics(i)]
// so the top-of-loop wait for eload(i+1) is vmcnt(32) — it drains loads and
// iteration-old atomics only, never fresh atomic acks (vmcnt retires in
// issue order, m135). W fragments live in LDS fragment-major
// ([k0][t][lane]*16B, conflict-free ds_read_b128, lgkmcnt) so MFMA operand
// reads never enter the vmcnt queue.
//
// Fragment layouts (mfma_f32_16x16x32_bf16, m89-verified):
//   A (lane l, elem j): e[n0 + (l&15)][32t + (l>>4)*8 + j]
//   B (lane l, elem j): W[k0*16 + (l&15)][32t + (l>>4)*8 + j]
//   C/D (lane l, reg r): h[n0 + (l>>4)*4 + r][k0*16 + (l&15)]
// ---------------------------------------------------------------------------
__global__ __launch_bounds__(256, 3) void fused_gemm_scatter(
    const float* __restrict__ e, const int* __restrict__ idx,
    const float* __restrict__ W, const float* __restrict__ bias_p,
    float* __restrict__ out, const unsigned* __restrict__ flag,
    int n_chunks) {
  __shared__ bf16x8 wlds[2048];  // 32 KiB: [k0][t][lane] fragment-major

  const int tid = threadIdx.x;
  const int wave = tid >> 6;
  const int lane = tid & 63;
  const int lr = lane & 15;
  const int lg = lane >> 4;

  // ---- one-time: stage W as bf16 fragments into LDS -----------------------
#pragma unroll
  for (int j = 0; j < 8; ++j) {
    const int g = (tid << 3) | j;      // 0..2047
    const int gl = g & 63;             // fragment lane
    const int tt = (g >> 6) & 3;       // K-step
    const int k0 = g >> 8;             // N-tile
    const int row = k0 * 16 + (gl & 15);
    const int col = tt * 32 + (gl >> 4) * 8;
    const float* src = W + (size_t)row * DIM + col;
    f32x4 w0 = *(const f32x4*)src;
    f32x4 w1 = *(const f32x4*)(src + 4);
    bf16x8 f;
    f[0] = (__bf16)w0[0]; f[1] = (__bf16)w0[1];
    f[2] = (__bf16)w0[2]; f[3] = (__bf16)w0[3];
    f[4] = (__bf16)w1[0]; f[5] = (__bf16)w1[1];
    f[6] = (__bf16)w1[2]; f[7] = (__bf16)w1[3];
    wlds[g] = f;
  }
  __syncthreads();

  const bool idx64 = (*flag == 0u);
  float bias[8];
#pragma unroll
  for (int k0 = 0; k0 < 8; ++k0) bias[k0] = bias_p[k0 * 16 + lr];

  int chunk = blockIdx.x;
  const int stride = gridDim.x;
  if (chunk >= n_chunks) return;  // block-uniform

  // ---- prologue: issue loads for first chunk ------------------------------
  f32x4 eload[8];
  int rows[4];
  {
    const int n0 = chunk * 64 + wave * 16;
    const float* erow = e + (size_t)(n0 + lr) * DIM + lg * 8;
#pragma unroll
    for (int t = 0; t < 4; ++t) {
      eload[2 * t]     = *(const f32x4*)(erow + t * 32);
      eload[2 * t + 1] = *(const f32x4*)(erow + t * 32 + 4);
    }
#pragma unroll
    for (int r = 0; r < 4; ++r) {
      const int n = n0 + lg * 4 + r;
      rows[r] = idx64 ? idx[2 * n] : idx[n];
    }
  }

  for (;;) {
    // 1. convert current e-tile (forces wait on eload; atomics stay queued)
    bf16x8 afrag[4];
#pragma unroll
    for (int t = 0; t < 4; ++t) {
      f32x4 a0 = eload[2 * t], a1 = eload[2 * t + 1];
      bf16x8 f;
      f[0] = (__bf16)a0[0]; f[1] = (__bf16)a0[1];
      f[2] = (__bf16)a0[2]; f[3] = (__bf16)a0[3];
      f[4] = (__bf16)a1[0]; f[5] = (__bf16)a1[1];
      f[6] = (__bf16)a1[2]; f[7] = (__bf16)a1[3];
      afrag[t] = f;
    }
    int currows[4];
#pragma unroll
    for (int r = 0; r < 4; ++r) currows[r] = rows[r];

    chunk += stride;
    const bool more = (chunk < n_chunks);  // block-uniform branch

    // 2. issue next chunk's loads BEFORE this chunk's atomics
    if (more) {
      const int n0 = chunk * 64 + wave * 16;
      const float* erow = e + (size_t)(n0 + lr) * DIM + lg * 8;
#pragma unroll
      for (int t = 0; t < 4; ++t) {
        eload[2 * t]     = *(const f32x4*)(erow + t * 32);
        eload[2 * t + 1] = *(const f32x4*)(erow + t * 32 + 4);
      }
#pragma unroll
      for (int r = 0; r < 4; ++r) {
        const int n = n0 + lg * 4 + r;
        rows[r] = idx64 ? idx[2 * n] : idx[n];
      }
    }

    // 3. MFMA — B operands from LDS (lgkmcnt, decoupled from vmcnt)
    f32x4 acc[8];
#pragma unroll
    for (int k0 = 0; k0 < 8; ++k0) acc[k0] = (f32x4){0.f, 0.f, 0.f, 0.f};
#pragma unroll
    for (int t = 0; t < 4; ++t) {
#pragma unroll
      for (int k0 = 0; k0 < 8; ++k0) {
        bf16x8 bf = wlds[(k0 * 4 + t) * 64 + lane];
        acc[k0] = __builtin_amdgcn_mfma_f32_16x16x32_bf16(afrag[t], bf,
                                                          acc[k0], 0, 0, 0);
      }
    }

    // 4. bias + ReLU + atomic scatter (acks drain one iteration later)
#pragma unroll
    for (int r = 0; r < 4; ++r) {
      float* orow = out + (size_t)currows[r] * DIM + lr;
#pragma unroll
      for (int k0 = 0; k0 < 8; ++k0) {
        float v = fmaxf(acc[k0][r] + bias[k0], 0.f);
        unsafeAtomicAdd(orow + k0 * 16, v);
      }
    }

    if (!more) break;
  }
}

extern "C" void kernel_launch(void* const* d_in, const int* in_sizes, int n_in,
                              void* d_out, int out_size, void* d_ws, size_t ws_size,
                              hipStream_t stream) {
  const float* e = (const float*)d_in[0];
  const int* idx = (const int*)d_in[1];
  const float* W = (const float*)d_in[2];
  const float* b = (const float*)d_in[3];
  float* out = (float*)d_out;
  unsigned* flag = (unsigned*)d_ws;

  const int n_e = in_sizes[0] / DIM;  // 1,600,000 rows

  hipMemsetAsync(d_out, 0, (size_t)out_size * sizeof(float), stream);
  hipMemsetAsync(flag, 0, sizeof(unsigned), stream);

  idx_probe_kernel<<<256, 256, 0, stream>>>((const unsigned*)idx, flag, n_e / 2);

  const int n_chunks = n_e / 64;  // 25,000 chunks of 64 rows
  fused_gemm_scatter<<<2048, 256, 0, stream>>>(e, idx, W, b, out, flag,
                                               n_chunks);
}